// Round 7
// baseline (217.292 us; speedup 1.0000x reference)
//
#include <hip/hip_runtime.h>
#include <math.h>

#define BB 32
#define NN 128
#define DD 64
#define EE (NN*NN)          // 16384
#define EPSI 1e-5f

typedef __attribute__((ext_vector_type(8))) short bf16x8;   // 8 bf16 (4 VGPRs)
typedef __attribute__((ext_vector_type(4))) float f32x4;

__device__ __forceinline__ short f2bf(float f) {
    union { float f; unsigned u; } v; v.f = f;
    unsigned u = v.u;
    unsigned r = (u + 0x7FFFu + ((u >> 16) & 1u)) >> 16;    // RNE
    return (short)r;
}
__device__ __forceinline__ float elu(float v) {
    return v > 0.f ? v : __expf(v) - 1.f;     // v_exp_f32 path
}

// ---------------------------------------------------------------------------
// k_fold: Mbf[d][k] = bf16( sum_o Wp[d][128+o] * We[o][k] )  (fc_e folded into fc_proj)
//         wbf[k]    = bf16( sum_o Wa[128+o]    * We[o][k] )  (fc_e folded into attn_fc)
__global__ void k_fold(const float* __restrict__ Wp, const float* __restrict__ We,
                       const float* __restrict__ Wa,
                       short* __restrict__ Mbf, short* __restrict__ wbf)
{
    int t = blockIdx.x * 256 + threadIdx.x;   // 0..4095
    int d = t >> 6, k = t & 63;
    float acc = 0.f;
    for (int o = 0; o < DD; ++o)
        acc += Wp[d*192 + 128 + o] * We[o*DD + k];
    Mbf[d*DD + k] = f2bf(acc);
    if (d == 0) {
        float aw = 0.f;
        for (int o = 0; o < DD; ++o)
            aw += Wa[128 + o] * We[o*DD + k];
        wbf[k] = f2bf(aw);
    }
}

// ---------------------------------------------------------------------------
// k_node: per (b,n) row: z_h = x @ Wh^T ;
//   PsT[n][frag(b,d)] = (z_h @ Wp[:, :64]^T)[d]    (MFMA C-fragment layout!)
//   PdT[n][frag(b,d)] = (z_h @ Wp[:, 64:128]^T)[d]
//   s = z_h . Wa[:64] ; t = z_h . Wa[64:128]
// frag(b,d) = ((b>>4)*4 + (d>>4))*256 + (((b>>2)&3)*16 + (d&15))*4 + (b&3)
__global__ void k_node(const float* __restrict__ x, const float* __restrict__ Wh,
                       const float* __restrict__ Wp, const float* __restrict__ Wa,
                       float* __restrict__ zh, float* __restrict__ PsT,
                       float* __restrict__ PdT, float* __restrict__ sO,
                       float* __restrict__ tO)
{
    int row = blockIdx.x;          // b*NN + n
    int b = row >> 7, n = row & 127;
    int d = threadIdx.x;           // 0..63
    __shared__ float xr[DD];
    __shared__ float zr[DD];
    xr[d] = x[row*DD + d];
    __syncthreads();
    float acc = 0.f;
#pragma unroll
    for (int k = 0; k < DD; ++k) acc += xr[k] * Wh[d*DD + k];
    zr[d] = acc;
    zh[row*DD + d] = acc;
    __syncthreads();
    float a0 = 0.f, a1 = 0.f;
#pragma unroll
    for (int o = 0; o < DD; ++o) {
        float z = zr[o];
        a0 += Wp[d*192 + o]      * z;
        a1 += Wp[d*192 + 64 + o] * z;
    }
    const int fi = ((b >> 4)*4 + (d >> 4))*256 + (((b >> 2) & 3)*16 + (d & 15))*4 + (b & 3);
    PsT[n*2048 + fi] = a0;
    PdT[n*2048 + fi] = a1;
    float sv = zr[d] * Wa[d];
    float tv = zr[d] * Wa[64 + d];
#pragma unroll
    for (int off = 32; off; off >>= 1) {
        sv += __shfl_xor(sv, off);
        tv += __shfl_xor(tv, off);
    }
    if (d == 0) { sO[row] = sv; tO[row] = tv; }
}

// ---------------------------------------------------------------------------
// k_edge v7 (bf16 MFMA, fragment-domain epilogue):
//   z = edge @ M^T + Ps[b,j] + Pd[b,i] -> BN(per-e over b,d) -> ELU
//   u[b,e] = edge . w  via a 5th MFMA B-tile (col0 = w)
// 256 threads = 4 waves; wave wv owns channel e = 4*blk + wv (32 b-rows x 64 d).
// acc is INITIALIZED with PsT[j0]+PdT[i0] (dense fragment-layout float4 loads,
// L2-hot, fully batchable). Stats/normalize/ELU run on fragments; the LDS
// repack happens post-normalize in two 16-row halves ([16][68] fp32/wave).
// INM: 0 = fp32 (B,E,D) input; 1 = bf16 (E,B,D) dense input
// OUTM: 0 = fp32 (B,E,D) output (d_out); 1 = bf16 (E,B,D) dense output
template <int INM, int OUTM>
__global__ __launch_bounds__(256, 4) void k_edge(
    const void* __restrict__ einv,
    const short* __restrict__ Mbf,   // (D,D) bf16
    const short* __restrict__ wbf,   // (D)   bf16
    const float* __restrict__ PsT,   // (N, 2048) fragment layout
    const float* __restrict__ PdT,   // (N, 2048) fragment layout
    const float* __restrict__ ge, const float* __restrict__ be,
    void* __restrict__ eoutv, float* __restrict__ uout)
{
    __shared__ float zl[4][16][68];
    const int l  = threadIdx.x & 63;
    const int wv = threadIdx.x >> 6;
    const int lr = l & 15;
    const int lg = l >> 4;
    const int e  = blockIdx.x * 4 + wv;
    const int i0 = e >> 7, j0 = e & 127;
    float (*Z)[68] = zl[wv];

    // ---- A fragments ----
    bf16x8 afr[2][2];                 // [m][k-half]
    if constexpr (INM == 0) {
        const float* ein = (const float*)einv;
#pragma unroll
        for (int m = 0; m < 2; ++m) {
            const float* rowp = ein + ((size_t)(16*m + lr)*EE + e)*DD;
            const float4 v0 = *reinterpret_cast<const float4*>(rowp +      lg*8);
            const float4 v1 = *reinterpret_cast<const float4*>(rowp +      lg*8 + 4);
            const float4 v2 = *reinterpret_cast<const float4*>(rowp + 32 + lg*8);
            const float4 v3 = *reinterpret_cast<const float4*>(rowp + 32 + lg*8 + 4);
            afr[m][0][0]=f2bf(v0.x); afr[m][0][1]=f2bf(v0.y); afr[m][0][2]=f2bf(v0.z); afr[m][0][3]=f2bf(v0.w);
            afr[m][0][4]=f2bf(v1.x); afr[m][0][5]=f2bf(v1.y); afr[m][0][6]=f2bf(v1.z); afr[m][0][7]=f2bf(v1.w);
            afr[m][1][0]=f2bf(v2.x); afr[m][1][1]=f2bf(v2.y); afr[m][1][2]=f2bf(v2.z); afr[m][1][3]=f2bf(v2.w);
            afr[m][1][4]=f2bf(v3.x); afr[m][1][5]=f2bf(v3.y); afr[m][1][6]=f2bf(v3.z); afr[m][1][7]=f2bf(v3.w);
        }
    } else {
        const short* ein = (const short*)einv + (size_t)e*BB*DD;   // dense channel block
#pragma unroll
        for (int m = 0; m < 2; ++m)
#pragma unroll
            for (int s = 0; s < 2; ++s)
                afr[m][s] = *reinterpret_cast<const bf16x8*>(ein + (16*m + lr)*DD + s*32 + lg*8);
    }

    // ---- B fragments (M^T, bf16, L2-hot) + w fragment (col0 only) ----
    bf16x8 bfr[4][2];
#pragma unroll
    for (int n = 0; n < 4; ++n)
#pragma unroll
        for (int s = 0; s < 2; ++s)
            bfr[n][s] = *reinterpret_cast<const bf16x8*>(Mbf + (16*n + lr)*DD + s*32 + lg*8);
    const bf16x8 zerov = (bf16x8){0,0,0,0,0,0,0,0};
    bf16x8 wfrag[2];
#pragma unroll
    for (int s = 0; s < 2; ++s)
        wfrag[s] = (lr == 0) ? *reinterpret_cast<const bf16x8*>(wbf + s*32 + lg*8) : zerov;

    // ---- acc init = PsT[j0] + PdT[i0]: dense fragment-layout loads ----
    f32x4 acc[2][4];
    f32x4 uacc[2];
    {
        const float* psb = PsT + j0*2048;
        const float* pdb = PdT + i0*2048;
#pragma unroll
        for (int m = 0; m < 2; ++m) {
            uacc[m] = (f32x4){0.f, 0.f, 0.f, 0.f};
#pragma unroll
            for (int n = 0; n < 4; ++n) {
                const float4 a = *reinterpret_cast<const float4*>(psb + (m*4+n)*256 + l*4);
                const float4 c = *reinterpret_cast<const float4*>(pdb + (m*4+n)*256 + l*4);
                acc[m][n] = (f32x4){a.x+c.x, a.y+c.y, a.z+c.z, a.w+c.w};
            }
        }
    }

    // ---- MFMA: 16 z-tiles + 4 u-tiles ----
#pragma unroll
    for (int m = 0; m < 2; ++m) {
#pragma unroll
        for (int n = 0; n < 4; ++n)
            acc[m][n] = __builtin_amdgcn_mfma_f32_16x16x32_bf16(afr[m][0], bfr[n][0], acc[m][n], 0, 0, 0);
        uacc[m] = __builtin_amdgcn_mfma_f32_16x16x32_bf16(afr[m][0], wfrag[0], uacc[m], 0, 0, 0);
#pragma unroll
        for (int n = 0; n < 4; ++n)
            acc[m][n] = __builtin_amdgcn_mfma_f32_16x16x32_bf16(afr[m][1], bfr[n][1], acc[m][n], 0, 0, 0);
        uacc[m] = __builtin_amdgcn_mfma_f32_16x16x32_bf16(afr[m][1], wfrag[1], uacc[m], 0, 0, 0);
    }

    // ---- BN stats on fragments (channel == wave, 2048 elems) ----
    float s1 = 0.f, s2 = 0.f;
#pragma unroll
    for (int m = 0; m < 2; ++m)
#pragma unroll
        for (int n = 0; n < 4; ++n)
#pragma unroll
            for (int q = 0; q < 4; ++q) { float v = acc[m][n][q]; s1 += v; s2 += v*v; }
#pragma unroll
    for (int off = 1; off < 64; off <<= 1) {
        s1 += __shfl_xor(s1, off);
        s2 += __shfl_xor(s2, off);
    }
    const float mean = s1 * (1.f/2048.f);
    const float var  = s2 * (1.f/2048.f) - mean*mean;
    const float sc = ge[e] * rsqrtf(var + EPSI);
    const float sh = be[e] - mean*sc;

    // ---- normalize + ELU on fragments ----
#pragma unroll
    for (int m = 0; m < 2; ++m)
#pragma unroll
        for (int n = 0; n < 4; ++n)
#pragma unroll
            for (int q = 0; q < 4; ++q)
                acc[m][n][q] = elu(acc[m][n][q]*sc + sh);

    // ---- u store (col0 lanes hold u[b] for b = 16m+4lg+q) ----
    if (lr == 0) {
#pragma unroll
        for (int m = 0; m < 2; ++m)
#pragma unroll
            for (int q = 0; q < 4; ++q)
                uout[(size_t)(16*m + 4*lg + q)*EE + e] = uacc[m][q];
    }

    // ---- repack + store, one 16-row half at a time (per-wave LDS, no barrier) ----
#pragma unroll
    for (int h = 0; h < 2; ++h) {
#pragma unroll
        for (int n = 0; n < 4; ++n)
#pragma unroll
            for (int q = 0; q < 4; ++q)
                Z[4*lg + q][16*n + lr] = acc[h][n][q];
        __builtin_amdgcn_s_waitcnt(0);   // lgkmcnt(0): wave-local LDS RAW fence
        if constexpr (OUTM == 0) {
            float* eout = (float*)eoutv;
#pragma unroll
            for (int it = 0; it < 4; ++it) {
                const int rr = lg + 4*it;            // 0..15
                const int b  = 16*h + rr;
                float4 z = *reinterpret_cast<float4*>(&Z[rr][lr*4]);
                *reinterpret_cast<float4*>(eout + ((size_t)b*EE + e)*DD + lr*4) = z;
            }
        } else {
            short* eout = (short*)eoutv + (size_t)e*BB*DD;   // dense channel block
#pragma unroll
            for (int it = 0; it < 2; ++it) {
                const int rr = (l >> 3) + 8*it;      // 0..15
                const int b  = 16*h + rr;
                const int c0 = (l & 7)*8;
                float4 zlo = *reinterpret_cast<float4*>(&Z[rr][c0]);
                float4 zhi = *reinterpret_cast<float4*>(&Z[rr][c0+4]);
                bf16x8 o;
                o[0]=f2bf(zlo.x); o[1]=f2bf(zlo.y); o[2]=f2bf(zlo.z); o[3]=f2bf(zlo.w);
                o[4]=f2bf(zhi.x); o[5]=f2bf(zhi.y); o[6]=f2bf(zhi.z); o[7]=f2bf(zhi.w);
                *reinterpret_cast<bf16x8*>(eout + b*DD + c0) = o;
            }
        }
        __builtin_amdgcn_s_waitcnt(0);   // reads of half h done before half h+1 overwrites
    }
}

// ---------------------------------------------------------------------------
// k_attn: per (b,i): logits = lrelu(s[j] + t[i] + u[b,i*N+j]) -> softmax over j
//         agg[b,i,:] = sum_j attn_j * zh[b,j,:]
__global__ void k_attn(const float* __restrict__ sI, const float* __restrict__ tI,
                       const float* __restrict__ u, const float* __restrict__ zh,
                       float* __restrict__ agg)
{
    int blk = blockIdx.x; int b = blk >> 7, i = blk & 127;
    int l = threadIdx.x;
    __shared__ float at[NN];
    float ti = tI[blk];
    float l0 = sI[b*NN + l]      + ti + u[b*EE + i*NN + l];
    float l1 = sI[b*NN + l + 64] + ti + u[b*EE + i*NN + l + 64];
    l0 = l0 >= 0.f ? l0 : 0.01f*l0;
    l1 = l1 >= 0.f ? l1 : 0.01f*l1;
    float mx = fmaxf(l0, l1);
#pragma unroll
    for (int off = 32; off; off >>= 1) mx = fmaxf(mx, __shfl_xor(mx, off));
    float e0 = __expf(l0 - mx), e1 = __expf(l1 - mx);
    float sm = e0 + e1;
#pragma unroll
    for (int off = 32; off; off >>= 1) sm += __shfl_xor(sm, off);
    float inv = 1.f / sm;
    at[l]      = e0 * inv;
    at[l + 64] = e1 * inv;
    __syncthreads();
    float acc = 0.f;
    for (int j = 0; j < NN; ++j) acc += at[j] * zh[(b*NN + j)*DD + l];
    agg[(b*NN + i)*DD + l] = acc;
}

// ---------------------------------------------------------------------------
// k_vbn: vertex BN (channel i over b,d) + residual + ELU
__global__ void k_vbn(const float* __restrict__ agg, const float* __restrict__ xres,
                      const float* __restrict__ gv, const float* __restrict__ bv,
                      float* __restrict__ xout)
{
    int i = blockIdx.x, t = threadIdx.x;
    float vals[8];
    float s1 = 0.f, s2 = 0.f;
#pragma unroll
    for (int q = 0; q < 8; ++q) {
        int m = t + 256*q; int b = m >> 6, d = m & 63;
        float v = agg[(b*NN + i)*DD + d];
        vals[q] = v; s1 += v; s2 += v*v;
    }
#pragma unroll
    for (int off = 1; off < 64; off <<= 1) {
        s1 += __shfl_xor(s1, off);
        s2 += __shfl_xor(s2, off);
    }
    __shared__ float r1[4], r2[4];
    int wv = t >> 6;
    if ((t & 63) == 0) { r1[wv] = s1; r2[wv] = s2; }
    __syncthreads();
    s1 = r1[0] + r1[1] + r1[2] + r1[3];
    s2 = r2[0] + r2[1] + r2[2] + r2[3];
    float mean  = s1 * (1.f/2048.f);
    float var   = s2 * (1.f/2048.f) - mean*mean;
    float scale = gv[i] * rsqrtf(var + EPSI);
    float shift = bv[i] - mean*scale;
#pragma unroll
    for (int q = 0; q < 8; ++q) {
        int m = t + 256*q; int b = m >> 6, d = m & 63;
        float v = vals[q]*scale + shift + xres[(b*NN + i)*DD + d];
        xout[(b*NN + i)*DD + d] = v > 0.f ? v : __expf(v) - 1.f;
    }
}

// ---------------------------------------------------------------------------
extern "C" void kernel_launch(void* const* d_in, const int* in_sizes, int n_in,
                              void* d_out, int out_size, void* d_ws, size_t ws_size,
                              hipStream_t stream)
{
    const float* x    = (const float*)d_in[0];
    const float* edge = (const float*)d_in[1];
    const float* Wh1  = (const float*)d_in[2];
    const float* We1  = (const float*)d_in[3];
    const float* Wp1  = (const float*)d_in[4];
    const float* Wa1  = (const float*)d_in[5];
    const float* Wh2  = (const float*)d_in[6];
    const float* We2  = (const float*)d_in[7];
    const float* Wp2  = (const float*)d_in[8];
    const float* Wa2  = (const float*)d_in[9];
    const float* gv1  = (const float*)d_in[10];
    const float* bv1  = (const float*)d_in[11];
    const float* ge1  = (const float*)d_in[12];
    const float* be1  = (const float*)d_in[13];
    const float* gv2  = (const float*)d_in[14];
    const float* bv2  = (const float*)d_in[15];
    const float* ge2  = (const float*)d_in[16];
    const float* be2  = (const float*)d_in[17];

    float* xout = (float*)d_out;                    // (B,N,D)
    float* eout = (float*)d_out + BB*NN*DD;         // (B,E,D) final edge output

    float* ws  = (float*)d_ws;
    short* Mbf = (short*)ws;  ws += DD*DD/2;        // bf16 M^T (8 KB)
    short* wbf = (short*)ws;  ws += DD/2;           // bf16 w
    float* zh  = ws;  ws += BB*NN*DD;
    float* PsT = ws;  ws += NN*BB*DD;               // fragment-layout Ps (1 MB)
    float* PdT = ws;  ws += NN*BB*DD;               // fragment-layout Pd (1 MB)
    float* sb  = ws;  ws += BB*NN;
    float* tb  = ws;  ws += BB*NN;
    float* ub  = ws;  ws += BB*EE;
    float* agg = ws;  ws += BB*NN*DD;
    float* x1  = ws;  ws += BB*NN*DD;
    short* e1bf = (short*)ws;                       // (E,B,D) bf16 intermediate (67 MB)
    const size_t need = ((size_t)(ws - (float*)d_ws))*4 + (size_t)EE*BB*DD*2;

    const bool dense = (ws_size >= need);

    // ----- layer 1 -----
    k_fold<<<16, 256, 0, stream>>>(Wp1, We1, Wa1, Mbf, wbf);
    k_node<<<BB*NN, 64, 0, stream>>>(x, Wh1, Wp1, Wa1, zh, PsT, PdT, sb, tb);
    if (dense)
        k_edge<0,1><<<EE/4, 256, 0, stream>>>(edge, Mbf, wbf, PsT, PdT, ge1, be1, e1bf, ub);
    else
        k_edge<0,0><<<EE/4, 256, 0, stream>>>(edge, Mbf, wbf, PsT, PdT, ge1, be1, eout, ub);
    k_attn<<<BB*NN, 64, 0, stream>>>(sb, tb, ub, zh, agg);
    k_vbn<<<NN, 256, 0, stream>>>(agg, x, gv1, bv1, x1);
    // ----- layer 2 -----
    k_fold<<<16, 256, 0, stream>>>(Wp2, We2, Wa2, Mbf, wbf);
    k_node<<<BB*NN, 64, 0, stream>>>(x1, Wh2, Wp2, Wa2, zh, PsT, PdT, sb, tb);
    if (dense)
        k_edge<1,0><<<EE/4, 256, 0, stream>>>(e1bf, Mbf, wbf, PsT, PdT, ge2, be2, eout, ub);
    else  // in-place on eout: each wave's reads precede its writes; disjoint e-rows
        k_edge<0,0><<<EE/4, 256, 0, stream>>>(eout, Mbf, wbf, PsT, PdT, ge2, be2, eout, ub);
    k_attn<<<BB*NN, 64, 0, stream>>>(sb, tb, ub, zh, agg);
    k_vbn<<<NN, 256, 0, stream>>>(agg, x1, gv2, bv2, xout);
}

// Round 8
// 208.639 us; speedup vs baseline: 1.0415x; 1.0415x over previous
//
#include <hip/hip_runtime.h>
#include <math.h>

#define BB 32
#define NN 128
#define DD 64
#define EE (NN*NN)          // 16384
#define EPSI 1e-5f

typedef __attribute__((ext_vector_type(8))) short bf16x8;   // 8 bf16 (4 VGPRs)
typedef __attribute__((ext_vector_type(4))) short s16x4;    // 4 bf16 (2 VGPRs)
typedef __attribute__((ext_vector_type(4))) float f32x4;

// lgkmcnt(0)-only wait: do NOT use __builtin_amdgcn_s_waitcnt(0) (drains vmcnt
// too -> per-wave store-ack stalls). sched_barrier stops hipcc hoisting past it.
#define LGKM0() do { asm volatile("s_waitcnt lgkmcnt(0)" ::: "memory"); \
                     __builtin_amdgcn_sched_barrier(0); } while (0)

__device__ __forceinline__ short f2bf(float f) {
    union { float f; unsigned u; } v; v.f = f;
    unsigned u = v.u;
    unsigned r = (u + 0x7FFFu + ((u >> 16) & 1u)) >> 16;    // RNE
    return (short)r;
}
__device__ __forceinline__ float elu(float v) {
    return v > 0.f ? v : __expf(v) - 1.f;     // v_exp_f32 path
}

// ---------------------------------------------------------------------------
// k_fold: Mbf[d][k] = bf16( sum_o Wp[d][128+o] * We[o][k] )  (fc_e folded into fc_proj)
//         wbf[k]    = bf16( sum_o Wa[128+o]    * We[o][k] )  (fc_e folded into attn_fc)
__global__ void k_fold(const float* __restrict__ Wp, const float* __restrict__ We,
                       const float* __restrict__ Wa,
                       short* __restrict__ Mbf, short* __restrict__ wbf)
{
    int t = blockIdx.x * 256 + threadIdx.x;   // 0..4095
    int d = t >> 6, k = t & 63;
    float acc = 0.f;
    for (int o = 0; o < DD; ++o)
        acc += Wp[d*192 + 128 + o] * We[o*DD + k];
    Mbf[d*DD + k] = f2bf(acc);
    if (d == 0) {
        float aw = 0.f;
        for (int o = 0; o < DD; ++o)
            aw += Wa[128 + o] * We[o*DD + k];
        wbf[k] = f2bf(aw);
    }
}

// ---------------------------------------------------------------------------
// k_node: per (b,n) row: z_h = x @ Wh^T ;
//   PsT[n][frag(b,d)] = (z_h @ Wp[:, :64]^T)[d]    (MFMA C-fragment layout)
//   PdT[n][frag(b,d)] = (z_h @ Wp[:, 64:128]^T)[d]
//   s = z_h . Wa[:64] ; t = z_h . Wa[64:128]
__global__ void k_node(const float* __restrict__ x, const float* __restrict__ Wh,
                       const float* __restrict__ Wp, const float* __restrict__ Wa,
                       float* __restrict__ zh, float* __restrict__ PsT,
                       float* __restrict__ PdT, float* __restrict__ sO,
                       float* __restrict__ tO)
{
    int row = blockIdx.x;          // b*NN + n
    int b = row >> 7, n = row & 127;
    int d = threadIdx.x;           // 0..63
    __shared__ float xr[DD];
    __shared__ float zr[DD];
    xr[d] = x[row*DD + d];
    __syncthreads();
    float acc = 0.f;
#pragma unroll
    for (int k = 0; k < DD; ++k) acc += xr[k] * Wh[d*DD + k];
    zr[d] = acc;
    zh[row*DD + d] = acc;
    __syncthreads();
    float a0 = 0.f, a1 = 0.f;
#pragma unroll
    for (int o = 0; o < DD; ++o) {
        float z = zr[o];
        a0 += Wp[d*192 + o]      * z;
        a1 += Wp[d*192 + 64 + o] * z;
    }
    const int fi = ((b >> 4)*4 + (d >> 4))*256 + (((b >> 2) & 3)*16 + (d & 15))*4 + (b & 3);
    PsT[n*2048 + fi] = a0;
    PdT[n*2048 + fi] = a1;
    float sv = zr[d] * Wa[d];
    float tv = zr[d] * Wa[64 + d];
#pragma unroll
    for (int off = 32; off; off >>= 1) {
        sv += __shfl_xor(sv, off);
        tv += __shfl_xor(tv, off);
    }
    if (d == 0) { sO[row] = sv; tO[row] = tv; }
}

// ---------------------------------------------------------------------------
// k_edge v8 (bf16 MFMA, LDS-staged A for the scattered fp32 layout):
//   z = edge @ M^T + Ps[b,j] + Pd[b,i] -> BN(per-e over b,d) -> ELU
//   u[b,e] = edge . w  via a 5th MFMA B-tile (col0 = w)
// 256 threads = 4 waves; wave wv owns channel e = 4*blk + wv (32 b x 64 d).
// INM==0: A is fp32 (B,E,D). Rows (b, e0..e0+3) are CONTIGUOUS 1KB runs ->
//   cooperative coalesced stage into bf16 LDS As[el][32][72] (conflict-free
//   for both the staged writes and the fragment ds_read_b128), then per-wave
//   fragment reads from its own el-section.
// INM==1: A is bf16 (E,B,D) dense -> direct coalesced fragment loads.
// Epilogue: BN stats + normalize + ELU on fragments (full-wave shfl), then
// repack through the (reused) per-wave LDS section with lgkmcnt-only waits.
// OUTM: 0 = fp32 (B,E,D) output (d_out); 1 = bf16 (E,B,D) dense output.
template <int INM, int OUTM>
__global__ __launch_bounds__(256, 4) void k_edge(
    const void* __restrict__ einv,
    const short* __restrict__ Mbf,   // (D,D) bf16
    const short* __restrict__ wbf,   // (D)   bf16
    const float* __restrict__ PsT,   // (N, 2048) fragment layout
    const float* __restrict__ PdT,   // (N, 2048) fragment layout
    const float* __restrict__ ge, const float* __restrict__ be,
    void* __restrict__ eoutv, float* __restrict__ uout)
{
    __shared__ short As[4][32][72];  // 18,432 B; staged A; reused as repack buf
    const int t  = threadIdx.x;
    const int l  = t & 63;
    const int wv = t >> 6;
    const int lr = l & 15;
    const int lg = l >> 4;
    const int e0 = blockIdx.x * 4;
    const int e  = e0 + wv;
    const int i0 = e >> 7, j0 = e & 127;

    // ---- A fragments ----
    bf16x8 afr[2][2];                 // [m][k-half]
    if constexpr (INM == 0) {
        const float* ein = (const float*)einv;
        const int tq = (t >> 4) & 3;          // el
        const int d0 = (t & 15) * 4;
        float4 sv[8];
#pragma unroll
        for (int it = 0; it < 8; ++it) {
            const int b = it*4 + wv;
            sv[it] = *reinterpret_cast<const float4*>(
                         ein + ((size_t)b*EE + e0 + tq)*DD + d0);
        }
#pragma unroll
        for (int it = 0; it < 8; ++it) {
            const int b = it*4 + wv;
            s16x4 o;
            o[0] = f2bf(sv[it].x); o[1] = f2bf(sv[it].y);
            o[2] = f2bf(sv[it].z); o[3] = f2bf(sv[it].w);
            *reinterpret_cast<s16x4*>(&As[tq][b][d0]) = o;
        }
        __syncthreads();
#pragma unroll
        for (int m = 0; m < 2; ++m)
#pragma unroll
            for (int s = 0; s < 2; ++s)
                afr[m][s] = *reinterpret_cast<const bf16x8*>(
                                &As[wv][16*m + lr][s*32 + lg*8]);
    } else {
        const short* ein = (const short*)einv + (size_t)e*BB*DD;   // dense block
#pragma unroll
        for (int m = 0; m < 2; ++m)
#pragma unroll
            for (int s = 0; s < 2; ++s)
                afr[m][s] = *reinterpret_cast<const bf16x8*>(
                                ein + (16*m + lr)*DD + s*32 + lg*8);
    }

    // ---- B fragments (M^T, bf16, L2-hot) + w fragment (col0 only) ----
    bf16x8 bfr[4][2];
#pragma unroll
    for (int n = 0; n < 4; ++n)
#pragma unroll
        for (int s = 0; s < 2; ++s)
            bfr[n][s] = *reinterpret_cast<const bf16x8*>(Mbf + (16*n + lr)*DD + s*32 + lg*8);
    const bf16x8 zerov = (bf16x8){0,0,0,0,0,0,0,0};
    bf16x8 wfrag[2];
#pragma unroll
    for (int s = 0; s < 2; ++s)
        wfrag[s] = (lr == 0) ? *reinterpret_cast<const bf16x8*>(wbf + s*32 + lg*8) : zerov;

    // ---- acc init = PsT[j0] + PdT[i0]: dense fragment-layout loads ----
    f32x4 acc[2][4];
    f32x4 uacc[2];
    {
        const float* psb = PsT + j0*2048;
        const float* pdb = PdT + i0*2048;
#pragma unroll
        for (int m = 0; m < 2; ++m) {
            uacc[m] = (f32x4){0.f, 0.f, 0.f, 0.f};
#pragma unroll
            for (int n = 0; n < 4; ++n) {
                const float4 a = *reinterpret_cast<const float4*>(psb + (m*4+n)*256 + l*4);
                const float4 c = *reinterpret_cast<const float4*>(pdb + (m*4+n)*256 + l*4);
                acc[m][n] = (f32x4){a.x+c.x, a.y+c.y, a.z+c.z, a.w+c.w};
            }
        }
    }

    // ---- MFMA: 16 z-tiles + 4 u-tiles ----
#pragma unroll
    for (int m = 0; m < 2; ++m) {
#pragma unroll
        for (int n = 0; n < 4; ++n)
            acc[m][n] = __builtin_amdgcn_mfma_f32_16x16x32_bf16(afr[m][0], bfr[n][0], acc[m][n], 0, 0, 0);
        uacc[m] = __builtin_amdgcn_mfma_f32_16x16x32_bf16(afr[m][0], wfrag[0], uacc[m], 0, 0, 0);
#pragma unroll
        for (int n = 0; n < 4; ++n)
            acc[m][n] = __builtin_amdgcn_mfma_f32_16x16x32_bf16(afr[m][1], bfr[n][1], acc[m][n], 0, 0, 0);
        uacc[m] = __builtin_amdgcn_mfma_f32_16x16x32_bf16(afr[m][1], wfrag[1], uacc[m], 0, 0, 0);
    }

    // ---- BN stats on fragments (channel == wave, 2048 elems) ----
    float s1 = 0.f, s2 = 0.f;
#pragma unroll
    for (int m = 0; m < 2; ++m)
#pragma unroll
        for (int n = 0; n < 4; ++n)
#pragma unroll
            for (int q = 0; q < 4; ++q) { float v = acc[m][n][q]; s1 += v; s2 += v*v; }
#pragma unroll
    for (int off = 1; off < 64; off <<= 1) {
        s1 += __shfl_xor(s1, off);
        s2 += __shfl_xor(s2, off);
    }
    const float mean = s1 * (1.f/2048.f);
    const float var  = s2 * (1.f/2048.f) - mean*mean;
    const float sc = ge[e] * rsqrtf(var + EPSI);
    const float sh = be[e] - mean*sc;

    // ---- normalize + ELU on fragments ----
#pragma unroll
    for (int m = 0; m < 2; ++m)
#pragma unroll
        for (int n = 0; n < 4; ++n)
#pragma unroll
            for (int q = 0; q < 4; ++q)
                acc[m][n][q] = elu(acc[m][n][q]*sc + sh);

    // ---- u store (col0 lanes hold u[b] for b = 16m+4lg+q) ----
    if (lr == 0) {
#pragma unroll
        for (int m = 0; m < 2; ++m)
#pragma unroll
            for (int q = 0; q < 4; ++q)
                uout[(size_t)(16*m + 4*lg + q)*EE + e] = uacc[m][q];
    }

    // ---- repack + store, 16-row halves through this wave's own LDS section ----
    float (*Z)[68] = reinterpret_cast<float (*)[68]>(&As[wv][0][0]);  // 4352 B < 4608 B section
    LGKM0();                              // fragment reads of As[wv] fully drained
#pragma unroll
    for (int h = 0; h < 2; ++h) {
#pragma unroll
        for (int n = 0; n < 4; ++n)
#pragma unroll
            for (int q = 0; q < 4; ++q)
                Z[4*lg + q][16*n + lr] = acc[h][n][q];
        LGKM0();                          // RAW: repack writes visible to reads
        if constexpr (OUTM == 0) {
            float* eout = (float*)eoutv;
#pragma unroll
            for (int it = 0; it < 4; ++it) {
                const int rr = lg + 4*it;            // 0..15
                const int b  = 16*h + rr;
                float4 z = *reinterpret_cast<float4*>(&Z[rr][lr*4]);
                *reinterpret_cast<float4*>(eout + ((size_t)b*EE + e)*DD + lr*4) = z;
            }
        } else {
            short* eout = (short*)eoutv + (size_t)e*BB*DD;   // dense channel block
#pragma unroll
            for (int it = 0; it < 2; ++it) {
                const int rr = (l >> 3) + 8*it;      // 0..15
                const int b  = 16*h + rr;
                const int c0 = (l & 7)*8;
                float4 zlo = *reinterpret_cast<float4*>(&Z[rr][c0]);
                float4 zhi = *reinterpret_cast<float4*>(&Z[rr][c0+4]);
                bf16x8 o;
                o[0]=f2bf(zlo.x); o[1]=f2bf(zlo.y); o[2]=f2bf(zlo.z); o[3]=f2bf(zlo.w);
                o[4]=f2bf(zhi.x); o[5]=f2bf(zhi.y); o[6]=f2bf(zhi.z); o[7]=f2bf(zhi.w);
                *reinterpret_cast<bf16x8*>(eout + b*DD + c0) = o;
            }
        }
        LGKM0();                          // WAR: half-h reads done before h+1 overwrite
    }
}

// ---------------------------------------------------------------------------
// k_attn: per (b,i): logits = lrelu(s[j] + t[i] + u[b,i*N+j]) -> softmax over j
//         agg[b,i,:] = sum_j attn_j * zh[b,j,:]
__global__ void k_attn(const float* __restrict__ sI, const float* __restrict__ tI,
                       const float* __restrict__ u, const float* __restrict__ zh,
                       float* __restrict__ agg)
{
    int blk = blockIdx.x; int b = blk >> 7, i = blk & 127;
    int l = threadIdx.x;
    __shared__ float at[NN];
    float ti = tI[blk];
    float l0 = sI[b*NN + l]      + ti + u[b*EE + i*NN + l];
    float l1 = sI[b*NN + l + 64] + ti + u[b*EE + i*NN + l + 64];
    l0 = l0 >= 0.f ? l0 : 0.01f*l0;
    l1 = l1 >= 0.f ? l1 : 0.01f*l1;
    float mx = fmaxf(l0, l1);
#pragma unroll
    for (int off = 32; off; off >>= 1) mx = fmaxf(mx, __shfl_xor(mx, off));
    float e0 = __expf(l0 - mx), e1 = __expf(l1 - mx);
    float sm = e0 + e1;
#pragma unroll
    for (int off = 32; off; off >>= 1) sm += __shfl_xor(sm, off);
    float inv = 1.f / sm;
    at[l]      = e0 * inv;
    at[l + 64] = e1 * inv;
    __syncthreads();
    float acc = 0.f;
    for (int j = 0; j < NN; ++j) acc += at[j] * zh[(b*NN + j)*DD + l];
    agg[(b*NN + i)*DD + l] = acc;
}

// ---------------------------------------------------------------------------
// k_vbn: vertex BN (channel i over b,d) + residual + ELU
__global__ void k_vbn(const float* __restrict__ agg, const float* __restrict__ xres,
                      const float* __restrict__ gv, const float* __restrict__ bv,
                      float* __restrict__ xout)
{
    int i = blockIdx.x, t = threadIdx.x;
    float vals[8];
    float s1 = 0.f, s2 = 0.f;
#pragma unroll
    for (int q = 0; q < 8; ++q) {
        int m = t + 256*q; int b = m >> 6, d = m & 63;
        float v = agg[(b*NN + i)*DD + d];
        vals[q] = v; s1 += v; s2 += v*v;
    }
#pragma unroll
    for (int off = 1; off < 64; off <<= 1) {
        s1 += __shfl_xor(s1, off);
        s2 += __shfl_xor(s2, off);
    }
    __shared__ float r1[4], r2[4];
    int wv = t >> 6;
    if ((t & 63) == 0) { r1[wv] = s1; r2[wv] = s2; }
    __syncthreads();
    s1 = r1[0] + r1[1] + r1[2] + r1[3];
    s2 = r2[0] + r2[1] + r2[2] + r2[3];
    float mean  = s1 * (1.f/2048.f);
    float var   = s2 * (1.f/2048.f) - mean*mean;
    float scale = gv[i] * rsqrtf(var + EPSI);
    float shift = bv[i] - mean*scale;
#pragma unroll
    for (int q = 0; q < 8; ++q) {
        int m = t + 256*q; int b = m >> 6, d = m & 63;
        float v = vals[q]*scale + shift + xres[(b*NN + i)*DD + d];
        xout[(b*NN + i)*DD + d] = v > 0.f ? v : __expf(v) - 1.f;
    }
}

// ---------------------------------------------------------------------------
extern "C" void kernel_launch(void* const* d_in, const int* in_sizes, int n_in,
                              void* d_out, int out_size, void* d_ws, size_t ws_size,
                              hipStream_t stream)
{
    const float* x    = (const float*)d_in[0];
    const float* edge = (const float*)d_in[1];
    const float* Wh1  = (const float*)d_in[2];
    const float* We1  = (const float*)d_in[3];
    const float* Wp1  = (const float*)d_in[4];
    const float* Wa1  = (const float*)d_in[5];
    const float* Wh2  = (const float*)d_in[6];
    const float* We2  = (const float*)d_in[7];
    const float* Wp2  = (const float*)d_in[8];
    const float* Wa2  = (const float*)d_in[9];
    const float* gv1  = (const float*)d_in[10];
    const float* bv1  = (const float*)d_in[11];
    const float* ge1  = (const float*)d_in[12];
    const float* be1  = (const float*)d_in[13];
    const float* gv2  = (const float*)d_in[14];
    const float* bv2  = (const float*)d_in[15];
    const float* ge2  = (const float*)d_in[16];
    const float* be2  = (const float*)d_in[17];

    float* xout = (float*)d_out;                    // (B,N,D)
    float* eout = (float*)d_out + BB*NN*DD;         // (B,E,D) final edge output

    float* ws  = (float*)d_ws;
    short* Mbf = (short*)ws;  ws += DD*DD/2;        // bf16 M^T (8 KB)
    short* wbf = (short*)ws;  ws += DD/2;           // bf16 w
    float* zh  = ws;  ws += BB*NN*DD;
    float* PsT = ws;  ws += NN*BB*DD;               // fragment-layout Ps (1 MB)
    float* PdT = ws;  ws += NN*BB*DD;               // fragment-layout Pd (1 MB)
    float* sb  = ws;  ws += BB*NN;
    float* tb  = ws;  ws += BB*NN;
    float* ub  = ws;  ws += BB*EE;
    float* agg = ws;  ws += BB*NN*DD;
    float* x1  = ws;  ws += BB*NN*DD;
    short* e1bf = (short*)ws;                       // (E,B,D) bf16 intermediate (67 MB)
    const size_t need = ((size_t)(ws - (float*)d_ws))*4 + (size_t)EE*BB*DD*2;

    const bool dense = (ws_size >= need);

    // ----- layer 1 -----
    k_fold<<<16, 256, 0, stream>>>(Wp1, We1, Wa1, Mbf, wbf);
    k_node<<<BB*NN, 64, 0, stream>>>(x, Wh1, Wp1, Wa1, zh, PsT, PdT, sb, tb);
    if (dense)
        k_edge<0,1><<<EE/4, 256, 0, stream>>>(edge, Mbf, wbf, PsT, PdT, ge1, be1, e1bf, ub);
    else
        k_edge<0,0><<<EE/4, 256, 0, stream>>>(edge, Mbf, wbf, PsT, PdT, ge1, be1, eout, ub);
    k_attn<<<BB*NN, 64, 0, stream>>>(sb, tb, ub, zh, agg);
    k_vbn<<<NN, 256, 0, stream>>>(agg, x, gv1, bv1, x1);
    // ----- layer 2 -----
    k_fold<<<16, 256, 0, stream>>>(Wp2, We2, Wa2, Mbf, wbf);
    k_node<<<BB*NN, 64, 0, stream>>>(x1, Wh2, Wp2, Wa2, zh, PsT, PdT, sb, tb);
    if (dense)
        k_edge<1,0><<<EE/4, 256, 0, stream>>>(e1bf, Mbf, wbf, PsT, PdT, ge2, be2, eout, ub);
    else  // in-place on eout: staged reads complete at __syncthreads before any store
        k_edge<0,0><<<EE/4, 256, 0, stream>>>(eout, Mbf, wbf, PsT, PdT, ge2, be2, eout, ub);
    k_attn<<<BB*NN, 64, 0, stream>>>(sb, tb, ub, zh, agg);
    k_vbn<<<NN, 256, 0, stream>>>(agg, x1, gv2, bv2, xout);
}

// Round 9
// 206.387 us; speedup vs baseline: 1.0528x; 1.0109x over previous
//
#include <hip/hip_runtime.h>
#include <math.h>

#define BB 32
#define NN 128
#define DD 64
#define EE (NN*NN)          // 16384
#define EPSI 1e-5f

typedef __attribute__((ext_vector_type(8))) short bf16x8;   // 8 bf16 (4 VGPRs)
typedef __attribute__((ext_vector_type(4))) short s16x4;    // 4 bf16 (2 VGPRs)
typedef __attribute__((ext_vector_type(4))) float f32x4;

// lgkmcnt(0)-only wait (NOT __builtin_amdgcn_s_waitcnt(0): that drains vmcnt
// too -> store-ack stalls). sched_barrier stops hipcc hoisting past it.
#define LGKM0() do { asm volatile("s_waitcnt lgkmcnt(0)" ::: "memory"); \
                     __builtin_amdgcn_sched_barrier(0); } while (0)

__device__ __forceinline__ short f2bf(float f) {
    union { float f; unsigned u; } v; v.f = f;
    unsigned u = v.u;
    unsigned r = (u + 0x7FFFu + ((u >> 16) & 1u)) >> 16;    // RNE
    return (short)r;
}
__device__ __forceinline__ float bf2f(short s) {
    union { unsigned u; float f; } v; v.u = ((unsigned)(unsigned short)s) << 16;
    return v.f;
}
__device__ __forceinline__ float dot4(float4 a, float4 b) {
    return a.x*b.x + a.y*b.y + a.z*b.z + a.w*b.w;
}
__device__ __forceinline__ float elu(float v) {
    return v > 0.f ? v : __expf(v) - 1.f;     // v_exp_f32 path
}

// ---------------------------------------------------------------------------
// k_node (+ folded k_fold): blocks [0, B*N): per (b,n) row:
//   z_h = x @ Wh^T ; PsT/PdT in MFMA C-fragment layout ; s,t scalars.
// blocks [B*N, B*N+64): fold — Mbf[d][k] = bf16(sum_o Wp[d][128+o]*We[o][k]),
//   block ff==0 also wf32[k] = sum_o Wa[128+o]*We[o][k].
__global__ void k_node(const float* __restrict__ x, const float* __restrict__ Wh,
                       const float* __restrict__ Wp, const float* __restrict__ We,
                       const float* __restrict__ Wa,
                       float* __restrict__ zh, float* __restrict__ PsT,
                       float* __restrict__ PdT, float* __restrict__ sO,
                       float* __restrict__ tO,
                       short* __restrict__ Mbf, float* __restrict__ wf32)
{
    const int row = blockIdx.x;
    const int d = threadIdx.x;           // 0..63
    if (row >= BB*NN) {                  // ---- fold tail blocks ----
        const int ff = row - BB*NN;      // 0..63 == output row d'
        float acc = 0.f;
        for (int o = 0; o < DD; ++o)
            acc += Wp[ff*192 + 128 + o] * We[o*DD + d];
        Mbf[ff*DD + d] = f2bf(acc);
        if (ff == 0) {
            float aw = 0.f;
            for (int o = 0; o < DD; ++o)
                aw += Wa[128 + o] * We[o*DD + d];
            wf32[d] = aw;
        }
        return;
    }
    const int b = row >> 7, n = row & 127;
    __shared__ float xr[DD];
    __shared__ float zr[DD];
    xr[d] = x[row*DD + d];
    __syncthreads();
    float acc = 0.f;
#pragma unroll
    for (int k = 0; k < DD; ++k) acc += xr[k] * Wh[d*DD + k];
    zr[d] = acc;
    zh[row*DD + d] = acc;
    __syncthreads();
    float a0 = 0.f, a1 = 0.f;
#pragma unroll
    for (int o = 0; o < DD; ++o) {
        float z = zr[o];
        a0 += Wp[d*192 + o]      * z;
        a1 += Wp[d*192 + 64 + o] * z;
    }
    const int fi = ((b >> 4)*4 + (d >> 4))*256 + (((b >> 2) & 3)*16 + (d & 15))*4 + (b & 3);
    PsT[n*2048 + fi] = a0;
    PdT[n*2048 + fi] = a1;
    float sv = zr[d] * Wa[d];
    float tv = zr[d] * Wa[64 + d];
#pragma unroll
    for (int off = 32; off; off >>= 1) {
        sv += __shfl_xor(sv, off);
        tv += __shfl_xor(tv, off);
    }
    if (d == 0) { sO[row] = sv; tO[row] = tv; }
}

// ---------------------------------------------------------------------------
// k_edge v9 (bf16 MFMA, 2 channels/wave, 8/block):
//   z = edge @ M^T + Ps[b,j] + Pd[b,i] -> BN(per-e over b,d) -> ELU
//   u[b,e] = edge . w  (VALU: in-stage for INM==0, from fragments for INM==1)
// 256 threads = 4 waves; wave wv owns channels eA=8*blk+2*wv, eB=eA+1.
// INM==0: rows (b, e0..e0+7) are contiguous 2KB runs -> coalesced stage into
//   bf16 LDS As[8][32][72]; u computed from the staged fp32 values.
// INM==1: bf16 (E,B,D) dense -> direct fragment loads; u from fragments.
// Epilogue per channel: BN stats/normalize/ELU on fragments, repack through
// the wave's own LDS sections with lgkmcnt-only waits.
// OUTM: 0 = fp32 (B,E,D) (d_out); 1 = bf16 (E,B,D) dense.
template <int INM, int OUTM>
__global__ __launch_bounds__(256, 3) void k_edge(
    const void* __restrict__ einv,
    const short* __restrict__ Mbf,   // (D,D) bf16
    const float* __restrict__ wf32,  // (D)   fp32
    const float* __restrict__ PsT,   // (N, 2048) fragment layout
    const float* __restrict__ PdT,   // (N, 2048) fragment layout
    const float* __restrict__ ge, const float* __restrict__ be,
    void* __restrict__ eoutv, float* __restrict__ uout)
{
    __shared__ short As[8][32][72];  // 36,864 B; staged A; reused as repack buf
    const int t  = threadIdx.x;
    const int l  = t & 63;
    const int wv = t >> 6;
    const int lr = l & 15;
    const int lg = l >> 4;
    const int e0 = blockIdx.x * 8;
    const int i0 = e0 >> 7;          // same node i for the whole block (8 | 128)

    // ---- stage A (INM==0): 256 rows, coalesced 1KB per wave-instr ----
    if constexpr (INM == 0) {
        const float* ein = (const float*)einv;
        const int g  = t >> 4;            // 0..15
        const int d0 = (t & 15) * 4;
        const int el = g & 7;
        const int bb = g >> 3;            // 0/1
        const float4 wv4 = *reinterpret_cast<const float4*>(wf32 + d0);
        float4 sv[16];
#pragma unroll
        for (int it = 0; it < 16; ++it) {
            const int b = bb + 2*it;
            sv[it] = *reinterpret_cast<const float4*>(
                         ein + ((size_t)b*EE + e0 + el)*DD + d0);
        }
#pragma unroll
        for (int it = 0; it < 16; ++it) {
            const int b = bb + 2*it;
            s16x4 o;
            o[0] = f2bf(sv[it].x); o[1] = f2bf(sv[it].y);
            o[2] = f2bf(sv[it].z); o[3] = f2bf(sv[it].w);
            *reinterpret_cast<s16x4*>(&As[el][b][d0]) = o;
            float up = dot4(sv[it], wv4);          // u partial over d0..d0+3
            up += __shfl_xor(up, 1);
            up += __shfl_xor(up, 2);
            up += __shfl_xor(up, 4);
            up += __shfl_xor(up, 8);
            if ((t & 15) == 0) uout[(size_t)b*EE + e0 + el] = up;
        }
        __syncthreads();
    }

    // ---- B fragments (M^T, bf16, L2-hot), shared by both channels ----
    bf16x8 bfr[4][2];
#pragma unroll
    for (int n = 0; n < 4; ++n)
#pragma unroll
        for (int s = 0; s < 2; ++s)
            bfr[n][s] = *reinterpret_cast<const bf16x8*>(Mbf + (16*n + lr)*DD + s*32 + lg*8);

    float4 wlo[2], whi[2];               // only used on the INM==1 path
    if constexpr (INM == 1) {
#pragma unroll
        for (int s = 0; s < 2; ++s) {
            wlo[s] = *reinterpret_cast<const float4*>(wf32 + s*32 + lg*8);
            whi[s] = *reinterpret_cast<const float4*>(wf32 + s*32 + lg*8 + 4);
        }
    }

    // ---- per-channel accumulators (both channels live) ----
    f32x4 acc[2][2][4];                  // [ch][m][n]
#pragma unroll
    for (int ch = 0; ch < 2; ++ch) {
        const int e  = e0 + 2*wv + ch;
        const int j0 = e & 127;
        const float* psb = PsT + j0*2048;
        const float* pdb = PdT + i0*2048;
#pragma unroll
        for (int m = 0; m < 2; ++m)
#pragma unroll
            for (int n = 0; n < 4; ++n) {
                const float4 a = *reinterpret_cast<const float4*>(psb + (m*4+n)*256 + l*4);
                const float4 c = *reinterpret_cast<const float4*>(pdb + (m*4+n)*256 + l*4);
                acc[ch][m][n] = (f32x4){a.x+c.x, a.y+c.y, a.z+c.z, a.w+c.w};
            }
    }

    // ---- MFMA per channel (afr registers reused across channels) ----
#pragma unroll
    for (int ch = 0; ch < 2; ++ch) {
        const int e = e0 + 2*wv + ch;
        bf16x8 afr[2][2];
        if constexpr (INM == 0) {
#pragma unroll
            for (int m = 0; m < 2; ++m)
#pragma unroll
                for (int s = 0; s < 2; ++s)
                    afr[m][s] = *reinterpret_cast<const bf16x8*>(
                                    &As[2*wv + ch][16*m + lr][s*32 + lg*8]);
        } else {
            const short* ein = (const short*)einv + (size_t)e*BB*DD;
#pragma unroll
            for (int m = 0; m < 2; ++m)
#pragma unroll
                for (int s = 0; s < 2; ++s)
                    afr[m][s] = *reinterpret_cast<const bf16x8*>(
                                    ein + (16*m + lr)*DD + s*32 + lg*8);
            // u from fragments: rows b = 16m+lr, reduce over lg
#pragma unroll
            for (int m = 0; m < 2; ++m) {
                float up = 0.f;
#pragma unroll
                for (int s = 0; s < 2; ++s) {
                    up += bf2f(afr[m][s][0])*wlo[s].x + bf2f(afr[m][s][1])*wlo[s].y
                        + bf2f(afr[m][s][2])*wlo[s].z + bf2f(afr[m][s][3])*wlo[s].w
                        + bf2f(afr[m][s][4])*whi[s].x + bf2f(afr[m][s][5])*whi[s].y
                        + bf2f(afr[m][s][6])*whi[s].z + bf2f(afr[m][s][7])*whi[s].w;
                }
                up += __shfl_xor(up, 16);
                up += __shfl_xor(up, 32);
                if (lg == 0) uout[(size_t)(16*m + lr)*EE + e] = up;
            }
        }
#pragma unroll
        for (int m = 0; m < 2; ++m) {
#pragma unroll
            for (int n = 0; n < 4; ++n)
                acc[ch][m][n] = __builtin_amdgcn_mfma_f32_16x16x32_bf16(afr[m][0], bfr[n][0], acc[ch][m][n], 0, 0, 0);
#pragma unroll
            for (int n = 0; n < 4; ++n)
                acc[ch][m][n] = __builtin_amdgcn_mfma_f32_16x16x32_bf16(afr[m][1], bfr[n][1], acc[ch][m][n], 0, 0, 0);
        }
    }

    // ---- BN stats, both channels interleaved (independent shfl chains) ----
    float s1a = 0.f, s2a = 0.f, s1b = 0.f, s2b = 0.f;
#pragma unroll
    for (int m = 0; m < 2; ++m)
#pragma unroll
        for (int n = 0; n < 4; ++n)
#pragma unroll
            for (int q = 0; q < 4; ++q) {
                float va = acc[0][m][n][q]; s1a += va; s2a += va*va;
                float vb = acc[1][m][n][q]; s1b += vb; s2b += vb*vb;
            }
#pragma unroll
    for (int off = 1; off < 64; off <<= 1) {
        s1a += __shfl_xor(s1a, off);
        s2a += __shfl_xor(s2a, off);
        s1b += __shfl_xor(s1b, off);
        s2b += __shfl_xor(s2b, off);
    }
    float scs[2], shs[2];
    {
        const int eA = e0 + 2*wv;
        float mean = s1a * (1.f/2048.f);
        float var  = s2a * (1.f/2048.f) - mean*mean;
        scs[0] = ge[eA] * rsqrtf(var + EPSI);
        shs[0] = be[eA] - mean*scs[0];
        mean = s1b * (1.f/2048.f);
        var  = s2b * (1.f/2048.f) - mean*mean;
        scs[1] = ge[eA+1] * rsqrtf(var + EPSI);
        shs[1] = be[eA+1] - mean*scs[1];
    }

    // ---- normalize + ELU on fragments ----
#pragma unroll
    for (int ch = 0; ch < 2; ++ch)
#pragma unroll
        for (int m = 0; m < 2; ++m)
#pragma unroll
            for (int n = 0; n < 4; ++n)
#pragma unroll
                for (int q = 0; q < 4; ++q)
                    acc[ch][m][n][q] = elu(acc[ch][m][n][q]*scs[ch] + shs[ch]);

    // ---- repack + store per channel through the wave's own LDS sections ----
    LGKM0();                              // all fragment reads of As drained
#pragma unroll
    for (int ch = 0; ch < 2; ++ch) {
        const int e = e0 + 2*wv + ch;
        float (*Z)[68] = reinterpret_cast<float (*)[68]>(&As[2*wv + ch][0][0]); // 4352B < 4608B
#pragma unroll
        for (int h = 0; h < 2; ++h) {
#pragma unroll
            for (int n = 0; n < 4; ++n)
#pragma unroll
                for (int q = 0; q < 4; ++q)
                    Z[4*lg + q][16*n + lr] = acc[ch][h][n][q];
            LGKM0();                      // RAW: repack writes visible
            if constexpr (OUTM == 0) {
                float* eout = (float*)eoutv;
#pragma unroll
                for (int it = 0; it < 4; ++it) {
                    const int rr = lg + 4*it;
                    const int b  = 16*h + rr;
                    float4 z = *reinterpret_cast<float4*>(&Z[rr][lr*4]);
                    *reinterpret_cast<float4*>(eout + ((size_t)b*EE + e)*DD + lr*4) = z;
                }
            } else {
                short* eout = (short*)eoutv + (size_t)e*BB*DD;
#pragma unroll
                for (int it = 0; it < 2; ++it) {
                    const int rr = (l >> 3) + 8*it;
                    const int b  = 16*h + rr;
                    const int c0 = (l & 7)*8;
                    float4 zlo = *reinterpret_cast<float4*>(&Z[rr][c0]);
                    float4 zhi = *reinterpret_cast<float4*>(&Z[rr][c0+4]);
                    bf16x8 o;
                    o[0]=f2bf(zlo.x); o[1]=f2bf(zlo.y); o[2]=f2bf(zlo.z); o[3]=f2bf(zlo.w);
                    o[4]=f2bf(zhi.x); o[5]=f2bf(zhi.y); o[6]=f2bf(zhi.z); o[7]=f2bf(zhi.w);
                    *reinterpret_cast<bf16x8*>(eout + b*DD + c0) = o;
                }
            }
            LGKM0();                      // WAR: half-h reads done before overwrite
        }
    }
}

// ---------------------------------------------------------------------------
// k_attn: per (b,i): logits = lrelu(s[j] + t[i] + u[b,i*N+j]) -> softmax over j
//         agg[b,i,:] = sum_j attn_j * zh[b,j,:]
__global__ void k_attn(const float* __restrict__ sI, const float* __restrict__ tI,
                       const float* __restrict__ u, const float* __restrict__ zh,
                       float* __restrict__ agg)
{
    int blk = blockIdx.x; int b = blk >> 7, i = blk & 127;
    int l = threadIdx.x;
    __shared__ float at[NN];
    float ti = tI[blk];
    float l0 = sI[b*NN + l]      + ti + u[b*EE + i*NN + l];
    float l1 = sI[b*NN + l + 64] + ti + u[b*EE + i*NN + l + 64];
    l0 = l0 >= 0.f ? l0 : 0.01f*l0;
    l1 = l1 >= 0.f ? l1 : 0.01f*l1;
    float mx = fmaxf(l0, l1);
#pragma unroll
    for (int off = 32; off; off >>= 1) mx = fmaxf(mx, __shfl_xor(mx, off));
    float e0 = __expf(l0 - mx), e1 = __expf(l1 - mx);
    float sm = e0 + e1;
#pragma unroll
    for (int off = 32; off; off >>= 1) sm += __shfl_xor(sm, off);
    float inv = 1.f / sm;
    at[l]      = e0 * inv;
    at[l + 64] = e1 * inv;
    __syncthreads();
    float acc = 0.f;
    for (int j = 0; j < NN; ++j) acc += at[j] * zh[(b*NN + j)*DD + l];
    agg[(b*NN + i)*DD + l] = acc;
}

// ---------------------------------------------------------------------------
// k_vbn: vertex BN (channel i over b,d) + residual + ELU
__global__ void k_vbn(const float* __restrict__ agg, const float* __restrict__ xres,
                      const float* __restrict__ gv, const float* __restrict__ bv,
                      float* __restrict__ xout)
{
    int i = blockIdx.x, t = threadIdx.x;
    float vals[8];
    float s1 = 0.f, s2 = 0.f;
#pragma unroll
    for (int q = 0; q < 8; ++q) {
        int m = t + 256*q; int b = m >> 6, d = m & 63;
        float v = agg[(b*NN + i)*DD + d];
        vals[q] = v; s1 += v; s2 += v*v;
    }
#pragma unroll
    for (int off = 1; off < 64; off <<= 1) {
        s1 += __shfl_xor(s1, off);
        s2 += __shfl_xor(s2, off);
    }
    __shared__ float r1[4], r2[4];
    int wv = t >> 6;
    if ((t & 63) == 0) { r1[wv] = s1; r2[wv] = s2; }
    __syncthreads();
    s1 = r1[0] + r1[1] + r1[2] + r1[3];
    s2 = r2[0] + r2[1] + r2[2] + r2[3];
    float mean  = s1 * (1.f/2048.f);
    float var   = s2 * (1.f/2048.f) - mean*mean;
    float scale = gv[i] * rsqrtf(var + EPSI);
    float shift = bv[i] - mean*scale;
#pragma unroll
    for (int q = 0; q < 8; ++q) {
        int m = t + 256*q; int b = m >> 6, d = m & 63;
        float v = vals[q]*scale + shift + xres[(b*NN + i)*DD + d];
        xout[(b*NN + i)*DD + d] = v > 0.f ? v : __expf(v) - 1.f;
    }
}

// ---------------------------------------------------------------------------
extern "C" void kernel_launch(void* const* d_in, const int* in_sizes, int n_in,
                              void* d_out, int out_size, void* d_ws, size_t ws_size,
                              hipStream_t stream)
{
    const float* x    = (const float*)d_in[0];
    const float* edge = (const float*)d_in[1];
    const float* Wh1  = (const float*)d_in[2];
    const float* We1  = (const float*)d_in[3];
    const float* Wp1  = (const float*)d_in[4];
    const float* Wa1  = (const float*)d_in[5];
    const float* Wh2  = (const float*)d_in[6];
    const float* We2  = (const float*)d_in[7];
    const float* Wp2  = (const float*)d_in[8];
    const float* Wa2  = (const float*)d_in[9];
    const float* gv1  = (const float*)d_in[10];
    const float* bv1  = (const float*)d_in[11];
    const float* ge1  = (const float*)d_in[12];
    const float* be1  = (const float*)d_in[13];
    const float* gv2  = (const float*)d_in[14];
    const float* bv2  = (const float*)d_in[15];
    const float* ge2  = (const float*)d_in[16];
    const float* be2  = (const float*)d_in[17];

    float* xout = (float*)d_out;                    // (B,N,D)
    float* eout = (float*)d_out + BB*NN*DD;         // (B,E,D) final edge output

    float* ws  = (float*)d_ws;
    short* Mbf = (short*)ws;  ws += DD*DD/2;        // bf16 M^T (8 KB)
    float* wf  = ws;  ws += DD;                     // fp32 w
    float* zh  = ws;  ws += BB*NN*DD;
    float* PsT = ws;  ws += NN*BB*DD;               // fragment-layout Ps (1 MB)
    float* PdT = ws;  ws += NN*BB*DD;               // fragment-layout Pd (1 MB)
    float* sb  = ws;  ws += BB*NN;
    float* tb  = ws;  ws += BB*NN;
    float* ub  = ws;  ws += BB*EE;
    float* agg = ws;  ws += BB*NN*DD;
    float* x1  = ws;  ws += BB*NN*DD;
    short* e1bf = (short*)ws;                       // (E,B,D) bf16 intermediate (67 MB)
    const size_t need = ((size_t)(ws - (float*)d_ws))*4 + (size_t)EE*BB*DD*2;

    const bool dense = (ws_size >= need);

    // ----- layer 1 -----
    k_node<<<BB*NN + 64, 64, 0, stream>>>(x, Wh1, Wp1, We1, Wa1, zh, PsT, PdT, sb, tb, Mbf, wf);
    if (dense)
        k_edge<0,1><<<EE/8, 256, 0, stream>>>(edge, Mbf, wf, PsT, PdT, ge1, be1, e1bf, ub);
    else
        k_edge<0,0><<<EE/8, 256, 0, stream>>>(edge, Mbf, wf, PsT, PdT, ge1, be1, eout, ub);
    k_attn<<<BB*NN, 64, 0, stream>>>(sb, tb, ub, zh, agg);
    k_vbn<<<NN, 256, 0, stream>>>(agg, x, gv1, bv1, x1);
    // ----- layer 2 -----
    k_node<<<BB*NN + 64, 64, 0, stream>>>(x1, Wh2, Wp2, We2, Wa2, zh, PsT, PdT, sb, tb, Mbf, wf);
    if (dense)
        k_edge<1,0><<<EE/8, 256, 0, stream>>>(e1bf, Mbf, wf, PsT, PdT, ge2, be2, eout, ub);
    else  // in-place on eout: staged reads complete at __syncthreads before stores
        k_edge<0,0><<<EE/8, 256, 0, stream>>>(eout, Mbf, wf, PsT, PdT, ge2, be2, eout, ub);
    k_attn<<<BB*NN, 64, 0, stream>>>(sb, tb, ub, zh, agg);
    k_vbn<<<NN, 256, 0, stream>>>(agg, x1, gv2, bv2, xout);
}